// Round 5
// baseline (117.774 us; speedup 1.0000x reference)
//
#include <hip/hip_runtime.h>

// LengthRegulator: x (B,DIM,T) f32, duration (B,T) i32 -> out (B,DIM,DMAX) f32, mel_len (B,) as f32
#define B_SZ   16
#define DIM_SZ 384
#define T_SZ   512
#define DMAX   4096
#define DC     4      // dims per block; grid (384/4=96, 16) = 1536 blocks = 6/CU, LDS 10KB

typedef float f4 __attribute__((ext_vector_type(4)));

// Single fused kernel. Per block: stage DC*T_SZ x-slice into LDS (coalesced f4
// loads issued first), wave 0 redundantly scans duration (2KB, L2-resident) via
// shfl, pad-region zero stores issued BEFORE the reg->LDS writes so ~56% of the
// write traffic overlaps the x-load latency, then LDS searchsorted + gather for
// valid frames. Nontemporal stores keep the 96MiB out stream from thrashing L2.
__global__ __launch_bounds__(256) void lr_fused_kernel(const float* __restrict__ x,
                                                       const int* __restrict__ duration,
                                                       float* __restrict__ out,
                                                       float* __restrict__ mel_out) {
    __shared__ float s_x[DC * T_SZ];   // 8 KB
    __shared__ int   s_cum[T_SZ];      // 2 KB
    __shared__ int   s_mel;
    const int tid = threadIdx.x;
    const int b   = blockIdx.y;
    const int d0  = blockIdx.x * DC;

    // 1) issue x staging loads into registers (kept in flight across the scan)
    const f4* __restrict__ xsrc = (const f4*)(x + ((size_t)b * DIM_SZ + d0) * T_SZ);
    const f4 r0 = xsrc[tid];
    const f4 r1 = xsrc[tid + 256];

    // 2) wave 0: shfl-scan of duration row (register prefix of 8 + 6-step wave scan)
    if (tid < 64) {
        const int4* __restrict__ dsrc = (const int4*)(duration + b * T_SZ);
        const int4 a = dsrc[tid * 2];
        const int4 c = dsrc[tid * 2 + 1];
        int p0 = a.x,      p1 = p0 + a.y, p2 = p1 + a.z, p3 = p2 + a.w;
        int p4 = p3 + c.x, p5 = p4 + c.y, p6 = p5 + c.z, p7 = p6 + c.w;
        int s = p7;
#pragma unroll
        for (int off = 1; off < 64; off <<= 1) {
            const int v = __shfl_up(s, off);
            if (tid >= off) s += v;
        }
        const int excl   = s - p7;
        const int rowsum = __shfl(s, 63);
        int4 o0, o1;
        if (rowsum == 0) {
            // reference: row_sum==0 -> duration := ones -> cum[t] = t+1
            const int t0 = tid * 8;
            o0 = make_int4(t0 + 1, t0 + 2, t0 + 3, t0 + 4);
            o1 = make_int4(t0 + 5, t0 + 6, t0 + 7, t0 + 8);
        } else {
            o0 = make_int4(excl + p0, excl + p1, excl + p2, excl + p3);
            o1 = make_int4(excl + p4, excl + p5, excl + p6, excl + p7);
        }
        int4* cdst = (int4*)s_cum;
        cdst[tid * 2]     = o0;
        cdst[tid * 2 + 1] = o1;
        if (tid == 63) {
            const int ml = (rowsum == 0) ? T_SZ : rowsum;
            s_mel = ml;
            if (blockIdx.x == 0) mel_out[b] = (float)ml;  // harness reads mel as f32
        }
    }
    __syncthreads();   // scan visible; x loads still in flight

    const int mel = s_mel;
    f4* __restrict__ outp = (f4*)(out + (size_t)b * DIM_SZ * DMAX);
    const f4 z = {0.f, 0.f, 0.f, 0.f};

    // 3) pad-region zero stores FIRST — no dependence on x, overlaps load latency
    bool need[4];
#pragma unroll
    for (int g = 0; g < 4; ++g) {
        const int f = g * 1024 + tid * 4;
        need[g] = (f < mel);
        if (!need[g]) {
            const int f4i = (f >> 2);
#pragma unroll
            for (int dd = 0; dd < DC; ++dd)
                __builtin_nontemporal_store(z, &outp[(size_t)(d0 + dd) * (DMAX / 4) + f4i]);
        }
    }

    // 4) registers -> LDS (first point that waits on the x loads)
    f4* s_x4 = (f4*)s_x;
    s_x4[tid]       = r0;
    s_x4[tid + 256] = r1;
    __syncthreads();

    // 5) searchsorted + gather for valid frame-groups, entirely out of LDS
#pragma unroll
    for (int g = 0; g < 4; ++g) {
        if (need[g]) {
            const int f = g * 1024 + tid * 4;
            int  idx[4];
            bool valid[4];
#pragma unroll
            for (int j = 0; j < 4; ++j) {
                const int ff = f + j;
                // branchless lower-bound: pos = #(cum <= ff), saturates at T-1 (== clip)
                int pos = 0;
#pragma unroll
                for (int step = 256; step > 0; step >>= 1) {
                    if (s_cum[pos + step - 1] <= ff) pos += step;
                }
                idx[j]   = pos;
                valid[j] = (ff < mel);
            }
            const int f4i = (f >> 2);
#pragma unroll
            for (int dd = 0; dd < DC; ++dd) {
                const float* __restrict__ xr = s_x + dd * T_SZ;
                f4 v;
                v.x = valid[0] ? xr[idx[0]] : 0.0f;
                v.y = valid[1] ? xr[idx[1]] : 0.0f;
                v.z = valid[2] ? xr[idx[2]] : 0.0f;
                v.w = valid[3] ? xr[idx[3]] : 0.0f;
                __builtin_nontemporal_store(v, &outp[(size_t)(d0 + dd) * (DMAX / 4) + f4i]);
            }
        }
    }
}

extern "C" void kernel_launch(void* const* d_in, const int* in_sizes, int n_in,
                              void* d_out, int out_size, void* d_ws, size_t ws_size,
                              hipStream_t stream) {
    const float* x        = (const float*)d_in[0];
    const int*   duration = (const int*)d_in[1];
    // d_in[2] is d_max == 4096, static for this problem instance.

    float* out     = (float*)d_out;
    float* mel_out = out + (size_t)B_SZ * DIM_SZ * DMAX;

    dim3 grid(DIM_SZ / DC, B_SZ);
    lr_fused_kernel<<<grid, 256, 0, stream>>>(x, duration, out, mel_out);
}

// Round 6
// 116.546 us; speedup vs baseline: 1.0105x; 1.0105x over previous
//
#include <hip/hip_runtime.h>

// LengthRegulator: x (B,DIM,T) f32, duration (B,T) i32 -> out (B,DIM,DMAX) f32, mel_len (B,) as f32
#define B_SZ   16
#define DIM_SZ 384
#define T_SZ   512
#define DMAX   4096
#define DC     4      // dims per block; grid (96,16)=1536 blocks = 6/CU, LDS 18KB -> 8/CU cap

typedef float f4 __attribute__((ext_vector_type(4)));

// Single fused kernel, searchsorted replaced by scatter-expand:
//   idx[f] = t  for f in [cum[t-1], cum[t])  — each thread scatter-writes its
// timestep id into a u16 LDS table (total writes = mel ~1792/block, vs 36,864
// ds_reads for the 9-step binary search it replaces). Gather reads idx4 as one
// ds_read_b64, clamps to T-1 (tail entries may be uninitialized; they're
// blended out by the valid mask — clamp only keeps the s_x read in-bounds).
__global__ __launch_bounds__(256) void lr_fused_kernel(const float* __restrict__ x,
                                                       const int* __restrict__ duration,
                                                       float* __restrict__ out,
                                                       float* __restrict__ mel_out) {
    __shared__ float          s_x[DC * T_SZ];   // 8 KB
    __shared__ int            s_cum[T_SZ];      // 2 KB
    __shared__ unsigned short s_idx[DMAX];      // 8 KB
    __shared__ int            s_mel;
    const int tid = threadIdx.x;
    const int b   = blockIdx.y;
    const int d0  = blockIdx.x * DC;

    // 1) issue x staging loads into registers (kept in flight across scan+scatter)
    const f4* __restrict__ xsrc = (const f4*)(x + ((size_t)b * DIM_SZ + d0) * T_SZ);
    const f4 r0 = xsrc[tid];
    const f4 r1 = xsrc[tid + 256];

    // 2) wave 0: shfl-scan of duration row (register prefix of 8 + 6-step wave scan)
    if (tid < 64) {
        const int4* __restrict__ dsrc = (const int4*)(duration + b * T_SZ);
        const int4 a = dsrc[tid * 2];
        const int4 c = dsrc[tid * 2 + 1];
        int p0 = a.x,      p1 = p0 + a.y, p2 = p1 + a.z, p3 = p2 + a.w;
        int p4 = p3 + c.x, p5 = p4 + c.y, p6 = p5 + c.z, p7 = p6 + c.w;
        int s = p7;
#pragma unroll
        for (int off = 1; off < 64; off <<= 1) {
            const int v = __shfl_up(s, off);
            if (tid >= off) s += v;
        }
        const int excl   = s - p7;
        const int rowsum = __shfl(s, 63);
        int4 o0, o1;
        if (rowsum == 0) {
            // reference: row_sum==0 -> duration := ones -> cum[t] = t+1
            const int t0 = tid * 8;
            o0 = make_int4(t0 + 1, t0 + 2, t0 + 3, t0 + 4);
            o1 = make_int4(t0 + 5, t0 + 6, t0 + 7, t0 + 8);
        } else {
            o0 = make_int4(excl + p0, excl + p1, excl + p2, excl + p3);
            o1 = make_int4(excl + p4, excl + p5, excl + p6, excl + p7);
        }
        int4* cdst = (int4*)s_cum;
        cdst[tid * 2]     = o0;
        cdst[tid * 2 + 1] = o1;
        if (tid == 63) {
            const int ml = (rowsum == 0) ? T_SZ : rowsum;
            s_mel = ml;
            if (blockIdx.x == 0) mel_out[b] = (float)ml;  // harness reads mel as f32
        }
    }
    __syncthreads();   // s_cum/s_mel visible; x loads still in flight

    const int mel = s_mel;
    f4* __restrict__ outp = (f4*)(out + (size_t)b * DIM_SZ * DMAX);
    const f4 z = {0.f, 0.f, 0.f, 0.f};

    // 3) scatter-expand: thread covers timesteps tid and tid+256.
    //    duration < 8 so each range is <= 7 writes; total writes = mel.
#pragma unroll
    for (int h = 0; h < 2; ++h) {
        const int t  = tid + h * 256;
        const int lo = (t > 0) ? s_cum[t - 1] : 0;
        const int hi = s_cum[t];
        for (int p = lo; p < hi; ++p) s_idx[p] = (unsigned short)t;
    }

    // 4) pad-region zero stores — independent of s_x/s_idx, overlaps x latency
    bool need[4];
#pragma unroll
    for (int g = 0; g < 4; ++g) {
        const int f = g * 1024 + tid * 4;
        need[g] = (f < mel);
        if (!need[g]) {
            const int f4i = (f >> 2);
#pragma unroll
            for (int dd = 0; dd < DC; ++dd)
                __builtin_nontemporal_store(z, &outp[(size_t)(d0 + dd) * (DMAX / 4) + f4i]);
        }
    }

    // 5) registers -> LDS (first point that waits on the x loads)
    f4* s_x4 = (f4*)s_x;
    s_x4[tid]       = r0;
    s_x4[tid + 256] = r1;
    __syncthreads();   // covers scatter + s_x

    // 6) gather valid frame-groups out of LDS
#pragma unroll
    for (int g = 0; g < 4; ++g) {
        if (need[g]) {
            const int f = g * 1024 + tid * 4;
            const ushort4 iv = *(const ushort4*)(s_idx + f);   // ds_read_b64, 8B-aligned
            int idx0 = min((int)iv.x, T_SZ - 1);
            int idx1 = min((int)iv.y, T_SZ - 1);
            int idx2 = min((int)iv.z, T_SZ - 1);
            int idx3 = min((int)iv.w, T_SZ - 1);
            const bool v0 = (f + 0) < mel, v1 = (f + 1) < mel;
            const bool v2 = (f + 2) < mel, v3 = (f + 3) < mel;
            const int f4i = (f >> 2);
#pragma unroll
            for (int dd = 0; dd < DC; ++dd) {
                const float* __restrict__ xr = s_x + dd * T_SZ;
                f4 v;
                v.x = v0 ? xr[idx0] : 0.0f;
                v.y = v1 ? xr[idx1] : 0.0f;
                v.z = v2 ? xr[idx2] : 0.0f;
                v.w = v3 ? xr[idx3] : 0.0f;
                __builtin_nontemporal_store(v, &outp[(size_t)(d0 + dd) * (DMAX / 4) + f4i]);
            }
        }
    }
}

extern "C" void kernel_launch(void* const* d_in, const int* in_sizes, int n_in,
                              void* d_out, int out_size, void* d_ws, size_t ws_size,
                              hipStream_t stream) {
    const float* x        = (const float*)d_in[0];
    const int*   duration = (const int*)d_in[1];
    // d_in[2] is d_max == 4096, static for this problem instance.

    float* out     = (float*)d_out;
    float* mel_out = out + (size_t)B_SZ * DIM_SZ * DMAX;

    dim3 grid(DIM_SZ / DC, B_SZ);
    lr_fused_kernel<<<grid, 256, 0, stream>>>(x, duration, out, mel_out);
}